// Round 4
// baseline (55310.858 us; speedup 1.0000x reference)
//
#include <hip/hip_runtime.h>

#define B_ 32
#define T_FULL 4096
#define EMB_ 256
#define XD_ 768
#define H_ 896
#define G3_ 2688
#define O_ 512
#define NWG_SCAN 28
#define THR_SCAN 512

typedef __attribute__((ext_vector_type(8))) short bf16x8;
typedef __attribute__((ext_vector_type(4))) float f32x4;

__device__ __forceinline__ f32x4 mfma16(bf16x8 a, bf16x8 b, f32x4 c) {
  return __builtin_amdgcn_mfma_f32_16x16x32_bf16(a, b, c, 0, 0, 0);
}

__device__ __forceinline__ unsigned short f2bf(float x) {
  union { float f; unsigned u; } v; v.f = x;
  unsigned r = v.u + 0x7fffu + ((v.u >> 16) & 1u);
  return (unsigned short)(r >> 16);
}
__device__ __forceinline__ float bf2f(unsigned short h) {
  union { float f; unsigned u; } v; v.u = ((unsigned)h) << 16;
  return v.f;
}

__device__ __forceinline__ unsigned long long aload64(const unsigned long long* p) {
  return __hip_atomic_load((unsigned long long*)p, __ATOMIC_RELAXED, __HIP_MEMORY_SCOPE_AGENT);
}
__device__ __forceinline__ unsigned aload32(const unsigned* p) {
  return __hip_atomic_load((unsigned*)p, __ATOMIC_RELAXED, __HIP_MEMORY_SCOPE_AGENT);
}
__device__ __forceinline__ void astore32(unsigned* p, unsigned v) {
  __hip_atomic_store(p, v, __ATOMIC_RELAXED, __HIP_MEMORY_SCOPE_AGENT);
}

__global__ __launch_bounds__(256) void cvt_bf16(const float* __restrict__ in,
                                                unsigned short* __restrict__ out, int n) {
  for (int i = blockIdx.x * 256 + threadIdx.x; i < n; i += gridDim.x * 256)
    out[i] = f2bf(in[i]);
}

// VAR: 0 = gates (A = concat(emb[sample], icnd) built on the fly, out fp32 [row][2688])
//      1 = fc1   (A = ornn bf16, out bf16 relu [row][896])
//      2 = fc2   (A = hidden bf16, out fp32 scattered to d_out [b][t][512])
template<int VAR>
__global__ __launch_bounds__(256) void gemm_bf16(
    const unsigned short* __restrict__ A,
    const int* __restrict__ sample,
    const float* __restrict__ icnd,
    const unsigned short* __restrict__ embb,
    const unsigned short* __restrict__ W,
    const float* __restrict__ bias,
    float* __restrict__ outf,
    unsigned short* __restrict__ outb,
    int t0) {
  constexpr int K = (VAR == 0) ? XD_ : H_;
  constexpr int N = (VAR == 0) ? G3_ : (VAR == 1 ? H_ : O_);
  constexpr int LDT = 48;
  __shared__ __align__(16) unsigned short Asl[128 * LDT];
  __shared__ __align__(16) unsigned short Bsl[128 * LDT];
  const int tid = threadIdx.x;
  const int rowBase = blockIdx.y * 128, colBase = blockIdx.x * 128;
  const int lane = tid & 63, wid = tid >> 6;
  const int wm = wid >> 1, wn = wid & 1;
  const int lr = lane & 15, lk = lane >> 4;
  const f32x4 fzero = {0.f, 0.f, 0.f, 0.f};
  f32x4 acc[4][4];
#pragma unroll
  for (int i = 0; i < 4; ++i)
#pragma unroll
    for (int j = 0; j < 4; ++j) acc[i][j] = fzero;

  for (int k0 = 0; k0 < K; k0 += 32) {
#pragma unroll
    for (int s = 0; s < 2; ++s) {
      const int seg = tid + s * 256;           // 512 segments of 8 elems
      const int r = seg >> 2, kg = (seg & 3) * 8;
      const int kk = k0 + kg;
      bf16x8 va;
      if (VAR == 0) {
        const int rowG = rowBase + r;
        const int b = rowG & 31, t = t0 + (rowG >> 5);
        if (kk < EMB_) {
          const int e = sample[b * T_FULL + t];
          va = *(const bf16x8*)(embb + e * EMB_ + kk);
        } else {
          const float* p = icnd + ((size_t)(b * T_FULL + t)) * 512 + (kk - EMB_);
          const float4 f0 = *(const float4*)p;
          const float4 f1 = *(const float4*)(p + 4);
          va[0] = (short)f2bf(f0.x); va[1] = (short)f2bf(f0.y);
          va[2] = (short)f2bf(f0.z); va[3] = (short)f2bf(f0.w);
          va[4] = (short)f2bf(f1.x); va[5] = (short)f2bf(f1.y);
          va[6] = (short)f2bf(f1.z); va[7] = (short)f2bf(f1.w);
        }
      } else {
        va = *(const bf16x8*)(A + (size_t)(rowBase + r) * K + kk);
      }
      *(bf16x8*)(Asl + r * LDT + kg) = va;
      *(bf16x8*)(Bsl + r * LDT + kg) = *(const bf16x8*)(W + (size_t)(colBase + r) * K + kk);
    }
    __syncthreads();
    bf16x8 af[4], bfr[4];
#pragma unroll
    for (int mt = 0; mt < 4; ++mt)
      af[mt] = *(const bf16x8*)(Asl + (wm * 64 + mt * 16 + lr) * LDT + lk * 8);
#pragma unroll
    for (int nt = 0; nt < 4; ++nt)
      bfr[nt] = *(const bf16x8*)(Bsl + (wn * 64 + nt * 16 + lr) * LDT + lk * 8);
#pragma unroll
    for (int mt = 0; mt < 4; ++mt)
#pragma unroll
      for (int nt = 0; nt < 4; ++nt) acc[mt][nt] = mfma16(af[mt], bfr[nt], acc[mt][nt]);
    __syncthreads();
  }

#pragma unroll
  for (int mt = 0; mt < 4; ++mt) {
#pragma unroll
    for (int nt = 0; nt < 4; ++nt) {
      const int colG = colBase + wn * 64 + nt * 16 + lr;
      const float bv = bias[colG];
#pragma unroll
      for (int r = 0; r < 4; ++r) {
        const int rowG = rowBase + wm * 64 + mt * 16 + lk * 4 + r;
        const float v = acc[mt][nt][r] + bv;
        if (VAR == 0) {
          outf[(size_t)rowG * N + colG] = v;
        } else if (VAR == 1) {
          outb[(size_t)rowG * N + colG] = f2bf(fmaxf(v, 0.f));
        } else {
          const int b = rowG & 31, t = t0 + (rowG >> 5);
          outf[((size_t)(b * T_FULL + t)) * O_ + colG] = v;
        }
      }
    }
  }
}

// Persistent GRU scan v4. 28 WGs x 512 threads (8 waves, 2/SIMD -> 256 VGPR budget).
// Per step:
//  P1 gather: 28 u64/thread register-staged (1 latency exposure) -> swizzled LDS
//  P2 MFMA: waves 0-3 only (m x cw); each A-frag read from LDS exactly once;
//     3 unit-tiles per wave, whh streamed from L1/L2; out -> gh2[96][33] unit-major
//  P3 elementwise GRU cell in regs; h stores (agent atomics) + ornn
//  P4 drain; arrival slot; gates(t+1) prefetch under the poll; lane-parallel poll
__global__ __launch_bounds__(THR_SCAN) void scan_gru(
    const float* __restrict__ gates,          // [Tc*32][2688] fp32
    const unsigned short* __restrict__ whh,   // [2688][896] bf16
    const float* __restrict__ bhh,            // [2688]
    unsigned long long* __restrict__ hbuf,    // [2][2][32][896] bf16 (rb,plane,b,j)
    unsigned short* __restrict__ ornn,        // [Tc*32][896] bf16
    unsigned int* __restrict__ arr,           // arrival slots (zeroed per call)
    int t0, int Tc) {
  __shared__ __align__(16) char hst[114688];  // [plane][32 rows][1792 B] swizzled
  __shared__ float gh2[96][33];               // [R = s*32+unit][batch]
  const int tid = threadIdx.x;
  const int j0 = blockIdx.x * 32;
  const int lane = tid & 63, wid = tid >> 6;
  const int lr = lane & 15, lk = lane >> 4;
  const int m = wid & 1, cw = wid >> 1;       // mfma identity (valid wid<4)
  const int eb = tid >> 4, ec = (tid & 15) * 2;  // elementwise identity

  // persistent per-thread constants
  float bh0, bh1, bh2, bh3, bh4, bh5;
  float hown0, hown1;
  {
    const int j = j0 + ec;
    bh0 = bhh[j];          bh1 = bhh[j + 1];
    bh2 = bhh[H_ + j];     bh3 = bhh[H_ + j + 1];
    bh4 = bhh[2 * H_ + j]; bh5 = bhh[2 * H_ + j + 1];
    const int rb0 = (t0 + 1) & 1;
    const unsigned short* hb = (const unsigned short*)hbuf;
    const unsigned hi01 = aload32((const unsigned*)(hb + rb0 * 57344 + eb * 896 + j));
    const unsigned lo01 = aload32((const unsigned*)(hb + rb0 * 57344 + 28672 + eb * 896 + j));
    hown0 = bf2f((unsigned short)(hi01 & 0xffff)) + bf2f((unsigned short)(lo01 & 0xffff));
    hown1 = bf2f((unsigned short)(hi01 >> 16)) + bf2f((unsigned short)(lo01 >> 16));
  }

  // whh fragment pointers for the 3 unit-tiles of this wave (wid<4 uses them)
  const unsigned short* wp0;
  const unsigned short* wp1;
  const unsigned short* wp2;
  {
    const int cwc = (cw < 2) ? cw : 0;  // clamp for non-mfma waves (no deref)
    const int t0i = cwc * 3;
    wp0 = whh + (size_t)((t0i >> 1) * H_ + j0 + ((t0i & 1) << 4) + lr) * H_ + lk * 8;
    const int t1i = cwc * 3 + 1;
    wp1 = whh + (size_t)((t1i >> 1) * H_ + j0 + ((t1i & 1) << 4) + lr) * H_ + lk * 8;
    const int t2i = cwc * 3 + 2;
    wp2 = whh + (size_t)((t2i >> 1) * H_ + j0 + ((t2i & 1) << 4) + lr) * H_ + lk * 8;
  }
  const int rowb = (m * 16 + lr) * 1792;
  const int sw = (lr & 7) << 4;
  const f32x4 fzero = {0.f, 0.f, 0.f, 0.f};

  // gates prefetch registers (for current tl)
  float2 pxr, pxz, pxn;
  {
    const float* gx = gates + (size_t)eb * G3_;
    pxr = *(const float2*)(gx + j0 + ec);
    pxz = *(const float2*)(gx + H_ + j0 + ec);
    pxn = *(const float2*)(gx + 2 * H_ + j0 + ec);
  }

  for (int tl = 0; tl < Tc; ++tl) {
    const int t = t0 + tl;
    const int rb = (t + 1) & 1, wb = t & 1;

    // ---- P1: register-staged cooperative gather (28 x u64 per thread) ----
    {
      const unsigned long long* src = hbuf + (size_t)rb * 14336 + tid;
      unsigned long long rg[28];
#pragma unroll
      for (int k = 0; k < 28; ++k) rg[k] = aload64(src + k * 512);
#pragma unroll
      for (int k = 0; k < 28; ++k) {
        const int i = tid + k * 512;
        const int p = (i >= 7168) ? 1 : 0;
        const int w = i - p * 7168;
        const int row = (int)(((unsigned)w * 18725u) >> 22);
        const int cb = (w - row * 224) * 8;
        const int dst = p * 57344 + row * 1792 + (cb ^ ((row & 7) << 4));
        *(unsigned long long*)(hst + dst) = rg[k];
      }
    }
    __syncthreads();

    // ---- P2: MFMA (waves 0-3), single LDS read per A-fragment ----
    if (wid < 4) {
      f32x4 acc[3][2];
#pragma unroll
      for (int u = 0; u < 3; ++u) { acc[u][0] = fzero; acc[u][1] = fzero; }
#pragma unroll
      for (int kk = 0; kk < 28; ++kk) {
        const int off = (lk * 16 + kk * 64) ^ sw;
        const bf16x8 ah = *(const bf16x8*)(hst + rowb + off);
        const bf16x8 al = *(const bf16x8*)(hst + 57344 + rowb + off);
        const bf16x8 b0 = *(const bf16x8*)(wp0 + kk * 32);
        acc[0][0] = mfma16(ah, b0, acc[0][0]);
        acc[0][1] = mfma16(al, b0, acc[0][1]);
        const bf16x8 b1 = *(const bf16x8*)(wp1 + kk * 32);
        acc[1][0] = mfma16(ah, b1, acc[1][0]);
        acc[1][1] = mfma16(al, b1, acc[1][1]);
        const bf16x8 b2 = *(const bf16x8*)(wp2 + kk * 32);
        acc[2][0] = mfma16(ah, b2, acc[2][0]);
        acc[2][1] = mfma16(al, b2, acc[2][1]);
      }
#pragma unroll
      for (int u = 0; u < 3; ++u)
#pragma unroll
        for (int r = 0; r < 4; ++r)
          gh2[(cw * 3 + u) * 16 + lr][m * 16 + lk * 4 + r] = acc[u][0][r] + acc[u][1][r];
    }
    __syncthreads();

    // ---- P3: elementwise GRU cell + h/ornn stores ----
    {
      const float ghr0 = gh2[ec][eb] + bh0,      ghr1 = gh2[ec + 1][eb] + bh1;
      const float ghz0 = gh2[32 + ec][eb] + bh2, ghz1 = gh2[33 + ec][eb] + bh3;
      const float ghn0 = gh2[64 + ec][eb] + bh4, ghn1 = gh2[65 + ec][eb] + bh5;
      const float r0 = 1.f / (1.f + __expf(-(pxr.x + ghr0)));
      const float r1 = 1.f / (1.f + __expf(-(pxr.y + ghr1)));
      const float z0 = 1.f / (1.f + __expf(-(pxz.x + ghz0)));
      const float z1 = 1.f / (1.f + __expf(-(pxz.y + ghz1)));
      const float e0 = __expf(2.f * (pxn.x + r0 * ghn0));
      const float e1 = __expf(2.f * (pxn.y + r1 * ghn1));
      const float n0 = 1.f - 2.f / (e0 + 1.f);
      const float n1 = 1.f - 2.f / (e1 + 1.f);
      hown0 = (1.f - z0) * n0 + z0 * hown0;
      hown1 = (1.f - z1) * n1 + z1 * hown1;
      const unsigned short h0 = f2bf(hown0), h1 = f2bf(hown1);
      const unsigned short l0 = f2bf(hown0 - bf2f(h0)), l1 = f2bf(hown1 - bf2f(h1));
      const unsigned hi01 = (unsigned)h0 | ((unsigned)h1 << 16);
      const unsigned lo01 = (unsigned)l0 | ((unsigned)l1 << 16);
      unsigned short* hb = (unsigned short*)hbuf;
      const int o = wb * 57344 + eb * 896 + j0 + ec;
      astore32((unsigned*)(hb + o), hi01);
      astore32((unsigned*)(hb + o + 28672), lo01);
      *(unsigned*)(ornn + ((size_t)tl * 32 + eb) * 896 + j0 + ec) = hi01;
    }

    // ---- P4: drain, arrive, prefetch next gates under the poll, poll ----
    asm volatile("s_waitcnt vmcnt(0)" ::: "memory");
    __syncthreads();
    const unsigned tgt = (unsigned)(t + 1);
    if (tid == 0) astore32(arr + blockIdx.x, tgt);
    if (tl + 1 < Tc) {
      const float* gx = gates + ((size_t)(tl + 1) * 32 + eb) * G3_;
      pxr = *(const float2*)(gx + j0 + ec);
      pxz = *(const float2*)(gx + H_ + j0 + ec);
      pxn = *(const float2*)(gx + 2 * H_ + j0 + ec);
    }
    if (wid == 0) {
      for (;;) {
        const unsigned v = (lane < NWG_SCAN) ? aload32(arr + lane) : tgt;
        if (__all(v >= tgt)) break;
        __builtin_amdgcn_s_sleep(1);
      }
    }
    __syncthreads();
  }
}

extern "C" void kernel_launch(void* const* d_in, const int* in_sizes, int n_in,
                              void* d_out, int out_size, void* d_ws, size_t ws_size,
                              hipStream_t stream) {
  (void)in_sizes; (void)n_in; (void)out_size;
  const int* sample = (const int*)d_in[0];
  const float* icnd = (const float*)d_in[1];
  const float* emb = (const float*)d_in[2];
  const float* wih = (const float*)d_in[3];
  const float* whh = (const float*)d_in[4];
  const float* bih = (const float*)d_in[5];
  const float* bhh = (const float*)d_in[6];
  const float* fc1w = (const float*)d_in[7];
  const float* fc1b = (const float*)d_in[8];
  const float* fc2w = (const float*)d_in[9];
  const float* fc2b = (const float*)d_in[10];
  float* out = (float*)d_out;
  char* ws = (char*)d_ws;

  size_t off = 0;
  auto alloc = [&](size_t bytes) {
    size_t o = off;
    off = (off + bytes + 255) & ~(size_t)255;
    return o;
  };
  const size_t o_arr = alloc(256);
  const size_t o_h = alloc((size_t)2 * 2 * 32 * H_ * 2);  // 229376 B
  const size_t zero_end = off;
  const size_t o_emb = alloc((size_t)O_ * EMB_ * 2);
  const size_t o_wih = alloc((size_t)G3_ * XD_ * 2);
  const size_t o_whh = alloc((size_t)G3_ * H_ * 2);
  const size_t o_f1w = alloc((size_t)H_ * H_ * 2);
  const size_t o_f2w = alloc((size_t)O_ * H_ * 2);
  const size_t head = off;

  int Tc = 512;
  while (Tc > 8) {
    size_t need = head + (size_t)Tc * 32 * G3_ * 4 + 2 * ((size_t)Tc * 32 * H_ * 2) + 4096;
    if (need <= ws_size) break;
    Tc >>= 1;
  }
  const size_t o_gat = alloc((size_t)Tc * 32 * G3_ * 4);
  const size_t o_orn = alloc((size_t)Tc * 32 * H_ * 2);
  const size_t o_hid = alloc((size_t)Tc * 32 * H_ * 2);
  (void)o_gat; (void)o_orn; (void)o_hid;

  unsigned short* embb = (unsigned short*)(ws + o_emb);
  unsigned short* wihb = (unsigned short*)(ws + o_wih);
  unsigned short* whhb = (unsigned short*)(ws + o_whh);
  unsigned short* f1wb = (unsigned short*)(ws + o_f1w);
  unsigned short* f2wb = (unsigned short*)(ws + o_f2w);
  float* gat = (float*)(ws + o_gat);
  unsigned short* orn = (unsigned short*)(ws + o_orn);
  unsigned short* hid = (unsigned short*)(ws + o_hid);
  unsigned long long* hbuf = (unsigned long long*)(ws + o_h);
  unsigned int* arr = (unsigned int*)(ws + o_arr);

  // zero arrival slots + h state (required every call: deterministic replays)
  (void)hipMemsetAsync(ws, 0, zero_end, stream);

  cvt_bf16<<<512, 256, 0, stream>>>(emb, embb, O_ * EMB_);
  cvt_bf16<<<1024, 256, 0, stream>>>(wih, wihb, G3_ * XD_);
  cvt_bf16<<<1024, 256, 0, stream>>>(whh, whhb, G3_ * H_);
  cvt_bf16<<<512, 256, 0, stream>>>(fc1w, f1wb, H_ * H_);
  cvt_bf16<<<512, 256, 0, stream>>>(fc2w, f2wb, O_ * H_);

  const int nch = T_FULL / Tc;
  const int M = Tc * 32;
  for (int c = 0; c < nch; ++c) {
    const int t0 = c * Tc;
    gemm_bf16<0><<<dim3(G3_ / 128, M / 128), 256, 0, stream>>>(
        nullptr, sample, icnd, embb, wihb, bih, gat, nullptr, t0);
    scan_gru<<<NWG_SCAN, THR_SCAN, 0, stream>>>(gat, whhb, bhh, hbuf, orn, arr, t0, Tc);
    gemm_bf16<1><<<dim3(H_ / 128, M / 128), 256, 0, stream>>>(
        orn, nullptr, nullptr, nullptr, f1wb, fc1b, nullptr, hid, t0);
    gemm_bf16<2><<<dim3(O_ / 128, M / 128), 256, 0, stream>>>(
        hid, nullptr, nullptr, nullptr, f2wb, fc2b, out, nullptr, t0);
  }
}